// Round 2
// baseline (547.871 us; speedup 1.0000x reference)
//
#include <hip/hip_runtime.h>

#define NTH 256
#define N_NODES 2048

// Symmetrized coefficient table layout in workspace (floats):
//   g3: 165 multisets x 12  (b30 s0..2 | b31 s0p0..s2p2)
//   g2:  45 multisets x  8  (b20 s0..1 | b21 s0p0..s1p2)
//   g1:   9 entries   x  4  (b10 | b11 p0..2)
#define G3_OFF 0
#define G2_OFF 1980   // 165*12
#define G1_OFF 2340   // +45*8
#define TAB_FLOATS 2376

// ---------------- prep: build symmetrized tables once, into global ws ----------------
__global__ void mace_prep(
    const float* __restrict__ b10, const float* __restrict__ b11,
    const float* __restrict__ b20, const float* __restrict__ b21,
    const float* __restrict__ b30, const float* __restrict__ b31,
    float* __restrict__ tab)
{
    const int tid = threadIdx.x;
    if (tid < 165) {
        // decode multiset rank -> (i<=j<=k)
        int i = 0, j = 0, k = 0;
        {
            int c = 0;
            for (int ii = 0; ii < 9; ii++)
                for (int jj = ii; jj < 9; jj++)
                    for (int kk = jj; kk < 9; kk++) {
                        if (c == tid) { i = ii; j = jj; k = kk; }
                        c++;
                    }
        }
        float s[12];
        #pragma unroll
        for (int q = 0; q < 12; q++) s[q] = 0.f;
        auto add3 = [&](int a, int b, int c2) {
            int o30 = ((a * 9 + b) * 9 + c2) * 3;   // b30: (9,9,9,3,1)
            int o31 = o30 * 3;                      // b31: (9,9,9,3,3)
            #pragma unroll
            for (int q = 0; q < 3; q++) s[q] += b30[o30 + q];
            #pragma unroll
            for (int q = 0; q < 9; q++) s[3 + q] += b31[o31 + q];
        };
        if (i == j && j == k) { add3(i, j, k); }
        else if (i == j)      { add3(i, i, k); add3(i, k, i); add3(k, i, i); }
        else if (j == k)      { add3(i, j, j); add3(j, i, j); add3(j, j, i); }
        else { add3(i,j,k); add3(i,k,j); add3(j,i,k); add3(j,k,i); add3(k,i,j); add3(k,j,i); }
        #pragma unroll
        for (int q = 0; q < 12; q++) tab[G3_OFF + tid * 12 + q] = s[q];
    } else if (tid < 210) {
        int t = tid - 165;
        int i = 0, j = 0;
        {
            int c = 0;
            for (int ii = 0; ii < 9; ii++)
                for (int jj = ii; jj < 9; jj++) {
                    if (c == t) { i = ii; j = jj; }
                    c++;
                }
        }
        float s[8];
        #pragma unroll
        for (int q = 0; q < 8; q++) s[q] = 0.f;
        auto add2 = [&](int a, int b) {
            int o20 = (a * 9 + b) * 2;   // b20: (9,9,2,1)
            int o21 = o20 * 3;           // b21: (9,9,2,3)
            #pragma unroll
            for (int q = 0; q < 2; q++) s[q] += b20[o20 + q];
            #pragma unroll
            for (int q = 0; q < 6; q++) s[2 + q] += b21[o21 + q];
        };
        if (i == j) add2(i, i); else { add2(i, j); add2(j, i); }
        #pragma unroll
        for (int q = 0; q < 8; q++) tab[G2_OFF + t * 8 + q] = s[q];
    } else if (tid < 219) {
        int a = tid - 210;
        tab[G1_OFF + a * 4 + 0] = b10[a];        // b10: (9,1,1)
        #pragma unroll
        for (int p = 0; p < 3; p++) tab[G1_OFF + a * 4 + 1 + p] = b11[a * 3 + p];  // b11: (9,1,3)
    }
}

// ---------------- main: 1 (node,mul) pair per thread, 4 blocks/CU ----------------
// 262144 threads -> 1024 blocks -> 4 blocks/CU -> 4 waves/SIMD (2x TLP vs RPT=2).
// 128 threads per node = 2 aligned waves, so spec[] / weight rows / table
// addresses remain wave-uniform (scalar loads); nf/out stay coalesced.
__global__ __launch_bounds__(NTH, 4) void mace_sc_kernel(
    const float* __restrict__ nf, const int* __restrict__ spec,
    const float* __restrict__ w10, const float* __restrict__ w11,
    const float* __restrict__ w20, const float* __restrict__ w21,
    const float* __restrict__ w30, const float* __restrict__ w31,
    const float* __restrict__ tab, float* __restrict__ out)
{
    const int g    = blockIdx.x * NTH + threadIdx.x;
    const int node = g >> 7;                   // 128 threads per node
    const int m    = g & 127;

    const float* nfp = nf + node * 1152;
    float f[9];
    f[0] = nfp[m];                                       // 0e block (128)
    #pragma unroll
    for (int j = 0; j < 3; j++) f[1 + j] = nfp[128 + m * 3 + j];   // 1o block
    #pragma unroll
    for (int j = 0; j < 5; j++) f[4 + j] = nfp[512 + m * 5 + j];   // 2e block

    const int z = spec[node];                  // wave-uniform

    float acc[4];
    #pragma unroll
    for (int p = 0; p < 4; p++) acc[p] = 0.f;

    // ---- nu = 3 ----  (fully unrolled: t compile-time, tab reads scalarize)
    {
        float t3[12];
        #pragma unroll
        for (int q = 0; q < 12; q++) t3[q] = 0.f;

        int t = 0;
        #pragma unroll
        for (int i = 0; i < 9; i++) {
            #pragma unroll
            for (int j = i; j < 9; j++) {
                const float fij = f[i] * f[j];
                #pragma unroll
                for (int k = j; k < 9; k++) {
                    const float* c = &tab[G3_OFF + t * 12];
                    const float m3 = fij * f[k];
                    #pragma unroll
                    for (int q = 0; q < 12; q++) t3[q] = fmaf(c[q], m3, t3[q]);
                    t++;
                }
            }
        }
        // weights: w30 (10,3,128) -> p=0 ; w31 (10,3,128) -> p=1..3
        const float* w30z = w30 + z * 3 * 128;
        const float* w31z = w31 + z * 3 * 128;
        #pragma unroll
        for (int s = 0; s < 3; s++) {
            const float wv = w30z[s * 128 + m];
            acc[0] = fmaf(wv, t3[s], acc[0]);
            const float wu = w31z[s * 128 + m];
            acc[1] = fmaf(wu, t3[3 + s * 3 + 0], acc[1]);
            acc[2] = fmaf(wu, t3[3 + s * 3 + 1], acc[2]);
            acc[3] = fmaf(wu, t3[3 + s * 3 + 2], acc[3]);
        }
    }

    // ---- nu = 2 ----
    {
        float t2[8];
        #pragma unroll
        for (int q = 0; q < 8; q++) t2[q] = 0.f;

        int t = 0;
        #pragma unroll
        for (int i = 0; i < 9; i++) {
            #pragma unroll
            for (int j = i; j < 9; j++) {
                const float* c = &tab[G2_OFF + t * 8];
                const float m2 = f[i] * f[j];
                #pragma unroll
                for (int q = 0; q < 8; q++) t2[q] = fmaf(c[q], m2, t2[q]);
                t++;
            }
        }
        const float* w20z = w20 + z * 2 * 128;
        const float* w21z = w21 + z * 2 * 128;
        #pragma unroll
        for (int s = 0; s < 2; s++) {
            const float wv = w20z[s * 128 + m];
            acc[0] = fmaf(wv, t2[s], acc[0]);
            const float wu = w21z[s * 128 + m];
            acc[1] = fmaf(wu, t2[2 + s * 3 + 0], acc[1]);
            acc[2] = fmaf(wu, t2[2 + s * 3 + 1], acc[2]);
            acc[3] = fmaf(wu, t2[2 + s * 3 + 2], acc[3]);
        }
    }

    // ---- nu = 1 ----
    {
        float t1[4];
        #pragma unroll
        for (int q = 0; q < 4; q++) t1[q] = 0.f;

        #pragma unroll
        for (int a = 0; a < 9; a++) {
            const float* c = &tab[G1_OFF + a * 4];
            #pragma unroll
            for (int q = 0; q < 4; q++) t1[q] = fmaf(c[q], f[a], t1[q]);
        }
        const float wv = w10[z * 128 + m];
        acc[0] = fmaf(wv, t1[0], acc[0]);
        const float wu = w11[z * 128 + m];
        acc[1] = fmaf(wu, t1[1], acc[1]);
        acc[2] = fmaf(wu, t1[2], acc[2]);
        acc[3] = fmaf(wu, t1[3], acc[3]);
    }

    // ---- store: out (n, 512) = [ (n,128) p=0 | (n,128,3) p=1..3 ] ----
    float* op = out + node * 512;
    op[m] = acc[0];
    #pragma unroll
    for (int p = 0; p < 3; p++) op[128 + m * 3 + p] = acc[1 + p];
}

extern "C" void kernel_launch(void* const* d_in, const int* in_sizes, int n_in,
                              void* d_out, int out_size, void* d_ws, size_t ws_size,
                              hipStream_t stream) {
    // setup_inputs() dict order is INTERLEAVED: node_feats, species,
    // b10, w10, b11, w11, b20, w20, b21, w21, b30, w30, b31, w31
    const float* nf  = (const float*)d_in[0];
    const int* spec  = (const int*)d_in[1];
    const float* b10 = (const float*)d_in[2];
    const float* w10 = (const float*)d_in[3];
    const float* b11 = (const float*)d_in[4];
    const float* w11 = (const float*)d_in[5];
    const float* b20 = (const float*)d_in[6];
    const float* w20 = (const float*)d_in[7];
    const float* b21 = (const float*)d_in[8];
    const float* w21 = (const float*)d_in[9];
    const float* b30 = (const float*)d_in[10];
    const float* w30 = (const float*)d_in[11];
    const float* b31 = (const float*)d_in[12];
    const float* w31 = (const float*)d_in[13];
    float* out = (float*)d_out;
    float* tab = (float*)d_ws;                 // needs TAB_FLOATS*4 = 9.5 KB

    mace_prep<<<1, 256, 0, stream>>>(b10, b11, b20, b21, b30, b31, tab);

    const int n_threads = N_NODES * 128;           // 262144, 1 pair/thread
    const int grid = n_threads / NTH;              // 1024 blocks -> 4 per CU
    mace_sc_kernel<<<grid, NTH, 0, stream>>>(
        nf, spec, w10, w11, w20, w21, w30, w31, tab, out);
}

// Round 3
// 116.665 us; speedup vs baseline: 4.6961x; 4.6961x over previous
//
#include <hip/hip_runtime.h>

#define NTH 256
#define N_NODES 2048

// Symmetrized coefficient table layout in workspace (floats):
//   g3: 165 multisets x 12  (b30 s0..2 | b31 s0p0..s2p2)
//   g2:  45 multisets x  8  (b20 s0..1 | b21 s0p0..s1p2)
//   g1:   9 entries   x  4  (b10 | b11 p0..2)
#define G3_OFF 0
#define G2_OFF 1980   // 165*12
#define G1_OFF 2340   // +45*8
#define TAB_FLOATS 2376

// ---------------- prep: build symmetrized tables once, into global ws ----------------
__global__ void mace_prep(
    const float* __restrict__ b10, const float* __restrict__ b11,
    const float* __restrict__ b20, const float* __restrict__ b21,
    const float* __restrict__ b30, const float* __restrict__ b31,
    float* __restrict__ tab)
{
    const int tid = threadIdx.x;
    if (tid < 165) {
        // decode multiset rank -> (i<=j<=k)
        int i = 0, j = 0, k = 0;
        {
            int c = 0;
            for (int ii = 0; ii < 9; ii++)
                for (int jj = ii; jj < 9; jj++)
                    for (int kk = jj; kk < 9; kk++) {
                        if (c == tid) { i = ii; j = jj; k = kk; }
                        c++;
                    }
        }
        float s[12];
        #pragma unroll
        for (int q = 0; q < 12; q++) s[q] = 0.f;
        auto add3 = [&](int a, int b, int c2) {
            int o30 = ((a * 9 + b) * 9 + c2) * 3;   // b30: (9,9,9,3,1)
            int o31 = o30 * 3;                      // b31: (9,9,9,3,3)
            #pragma unroll
            for (int q = 0; q < 3; q++) s[q] += b30[o30 + q];
            #pragma unroll
            for (int q = 0; q < 9; q++) s[3 + q] += b31[o31 + q];
        };
        if (i == j && j == k) { add3(i, j, k); }
        else if (i == j)      { add3(i, i, k); add3(i, k, i); add3(k, i, i); }
        else if (j == k)      { add3(i, j, j); add3(j, i, j); add3(j, j, i); }
        else { add3(i,j,k); add3(i,k,j); add3(j,i,k); add3(j,k,i); add3(k,i,j); add3(k,j,i); }
        #pragma unroll
        for (int q = 0; q < 12; q++) tab[G3_OFF + tid * 12 + q] = s[q];
    } else if (tid < 210) {
        int t = tid - 165;
        int i = 0, j = 0;
        {
            int c = 0;
            for (int ii = 0; ii < 9; ii++)
                for (int jj = ii; jj < 9; jj++) {
                    if (c == t) { i = ii; j = jj; }
                    c++;
                }
        }
        float s[8];
        #pragma unroll
        for (int q = 0; q < 8; q++) s[q] = 0.f;
        auto add2 = [&](int a, int b) {
            int o20 = (a * 9 + b) * 2;   // b20: (9,9,2,1)
            int o21 = o20 * 3;           // b21: (9,9,2,3)
            #pragma unroll
            for (int q = 0; q < 2; q++) s[q] += b20[o20 + q];
            #pragma unroll
            for (int q = 0; q < 6; q++) s[2 + q] += b21[o21 + q];
        };
        if (i == j) add2(i, i); else { add2(i, j); add2(j, i); }
        #pragma unroll
        for (int q = 0; q < 8; q++) tab[G2_OFF + t * 8 + q] = s[q];
    } else if (tid < 219) {
        int a = tid - 210;
        tab[G1_OFF + a * 4 + 0] = b10[a];        // b10: (9,1,1)
        #pragma unroll
        for (int p = 0; p < 3; p++) tab[G1_OFF + a * 4 + 1 + p] = b11[a * 3 + p];  // b11: (9,1,3)
    }
}

// ---------------- main: 1 (node,mul) pair per thread ----------------
// 262144 threads -> 1024 blocks -> 4 blocks/CU (grid supplies 4 waves/SIMD).
// launch_bounds min-waves kept at 2: round 2 showed that forcing 4 clamps the
// VGPR budget to 64 and spills ~1.2 GB of scratch per dispatch (FETCH 796 MB).
// The grid already provides the occupancy; we need the registers.
// 128 threads per node = 2 aligned waves -> spec[] / weight rows / table
// addresses are wave-uniform (scalar loads); nf/out stay coalesced.
__global__ __launch_bounds__(NTH, 2) void mace_sc_kernel(
    const float* __restrict__ nf, const int* __restrict__ spec,
    const float* __restrict__ w10, const float* __restrict__ w11,
    const float* __restrict__ w20, const float* __restrict__ w21,
    const float* __restrict__ w30, const float* __restrict__ w31,
    const float* __restrict__ tab, float* __restrict__ out)
{
    const int g    = blockIdx.x * NTH + threadIdx.x;
    const int node = g >> 7;                   // 128 threads per node
    const int m    = g & 127;

    const float* nfp = nf + node * 1152;
    float f[9];
    f[0] = nfp[m];                                       // 0e block (128)
    #pragma unroll
    for (int j = 0; j < 3; j++) f[1 + j] = nfp[128 + m * 3 + j];   // 1o block
    #pragma unroll
    for (int j = 0; j < 5; j++) f[4 + j] = nfp[512 + m * 5 + j];   // 2e block

    const int z = spec[node];                  // wave-uniform

    float acc[4];
    #pragma unroll
    for (int p = 0; p < 4; p++) acc[p] = 0.f;

    // ---- nu = 3 ----  (fully unrolled: t compile-time, tab reads scalarize)
    {
        float t3[12];
        #pragma unroll
        for (int q = 0; q < 12; q++) t3[q] = 0.f;

        int t = 0;
        #pragma unroll
        for (int i = 0; i < 9; i++) {
            #pragma unroll
            for (int j = i; j < 9; j++) {
                const float fij = f[i] * f[j];
                #pragma unroll
                for (int k = j; k < 9; k++) {
                    const float* c = &tab[G3_OFF + t * 12];
                    const float m3 = fij * f[k];
                    #pragma unroll
                    for (int q = 0; q < 12; q++) t3[q] = fmaf(c[q], m3, t3[q]);
                    t++;
                }
            }
        }
        // weights: w30 (10,3,128) -> p=0 ; w31 (10,3,128) -> p=1..3
        const float* w30z = w30 + z * 3 * 128;
        const float* w31z = w31 + z * 3 * 128;
        #pragma unroll
        for (int s = 0; s < 3; s++) {
            const float wv = w30z[s * 128 + m];
            acc[0] = fmaf(wv, t3[s], acc[0]);
            const float wu = w31z[s * 128 + m];
            acc[1] = fmaf(wu, t3[3 + s * 3 + 0], acc[1]);
            acc[2] = fmaf(wu, t3[3 + s * 3 + 1], acc[2]);
            acc[3] = fmaf(wu, t3[3 + s * 3 + 2], acc[3]);
        }
    }

    // ---- nu = 2 ----
    {
        float t2[8];
        #pragma unroll
        for (int q = 0; q < 8; q++) t2[q] = 0.f;

        int t = 0;
        #pragma unroll
        for (int i = 0; i < 9; i++) {
            #pragma unroll
            for (int j = i; j < 9; j++) {
                const float* c = &tab[G2_OFF + t * 8];
                const float m2 = f[i] * f[j];
                #pragma unroll
                for (int q = 0; q < 8; q++) t2[q] = fmaf(c[q], m2, t2[q]);
                t++;
            }
        }
        const float* w20z = w20 + z * 2 * 128;
        const float* w21z = w21 + z * 2 * 128;
        #pragma unroll
        for (int s = 0; s < 2; s++) {
            const float wv = w20z[s * 128 + m];
            acc[0] = fmaf(wv, t2[s], acc[0]);
            const float wu = w21z[s * 128 + m];
            acc[1] = fmaf(wu, t2[2 + s * 3 + 0], acc[1]);
            acc[2] = fmaf(wu, t2[2 + s * 3 + 1], acc[2]);
            acc[3] = fmaf(wu, t2[2 + s * 3 + 2], acc[3]);
        }
    }

    // ---- nu = 1 ----
    {
        float t1[4];
        #pragma unroll
        for (int q = 0; q < 4; q++) t1[q] = 0.f;

        #pragma unroll
        for (int a = 0; a < 9; a++) {
            const float* c = &tab[G1_OFF + a * 4];
            #pragma unroll
            for (int q = 0; q < 4; q++) t1[q] = fmaf(c[q], f[a], t1[q]);
        }
        const float wv = w10[z * 128 + m];
        acc[0] = fmaf(wv, t1[0], acc[0]);
        const float wu = w11[z * 128 + m];
        acc[1] = fmaf(wu, t1[1], acc[1]);
        acc[2] = fmaf(wu, t1[2], acc[2]);
        acc[3] = fmaf(wu, t1[3], acc[3]);
    }

    // ---- store: out (n, 512) = [ (n,128) p=0 | (n,128,3) p=1..3 ] ----
    float* op = out + node * 512;
    op[m] = acc[0];
    #pragma unroll
    for (int p = 0; p < 3; p++) op[128 + m * 3 + p] = acc[1 + p];
}

extern "C" void kernel_launch(void* const* d_in, const int* in_sizes, int n_in,
                              void* d_out, int out_size, void* d_ws, size_t ws_size,
                              hipStream_t stream) {
    // setup_inputs() dict order is INTERLEAVED: node_feats, species,
    // b10, w10, b11, w11, b20, w20, b21, w21, b30, w30, b31, w31
    const float* nf  = (const float*)d_in[0];
    const int* spec  = (const int*)d_in[1];
    const float* b10 = (const float*)d_in[2];
    const float* w10 = (const float*)d_in[3];
    const float* b11 = (const float*)d_in[4];
    const float* w11 = (const float*)d_in[5];
    const float* b20 = (const float*)d_in[6];
    const float* w20 = (const float*)d_in[7];
    const float* b21 = (const float*)d_in[8];
    const float* w21 = (const float*)d_in[9];
    const float* b30 = (const float*)d_in[10];
    const float* w30 = (const float*)d_in[11];
    const float* b31 = (const float*)d_in[12];
    const float* w31 = (const float*)d_in[13];
    float* out = (float*)d_out;
    float* tab = (float*)d_ws;                 // needs TAB_FLOATS*4 = 9.5 KB

    mace_prep<<<1, 256, 0, stream>>>(b10, b11, b20, b21, b30, b31, tab);

    const int n_threads = N_NODES * 128;           // 262144, 1 pair/thread
    const int grid = n_threads / NTH;              // 1024 blocks -> 4 per CU
    mace_sc_kernel<<<grid, NTH, 0, stream>>>(
        nf, spec, w10, w11, w20, w21, w30, w31, tab, out);
}